// Round 1
// baseline (89.897 us; speedup 1.0000x reference)
//
#include <hip/hip_runtime.h>

namespace {

constexpr int HIMG = 512;
constexpr int WIMG = 512;
constexpr int CH = 3;
constexpr int ROWF = WIMG * CH;        // 1536 floats per image row
constexpr int TW = 64;                 // output pixels per W-tile
constexpr int TF = TW * CH;            // 192 output floats per tile-row
constexpr int RF = (TW + 6) * CH;      // 210 staged floats per row (3px halo each side)
constexpr int RCH = 8;                 // rows per inner iteration
constexpr int HCHUNK = 128;            // output rows per block
constexpr int NITER = HCHUNK / RCH;    // 16
constexpr int NTHREADS = 256;
constexpr int OUTS_PER_THREAD = (RCH * TF) / NTHREADS; // 6

// exp(-x^2 / (2*1.5^2)) for x = 0..3, double precision (matches cv2.getGaussianKernel)
constexpr double KD0 = 0.13533528323661270;  // exp(-9/4.5) = exp(-2)
constexpr double KD1 = 0.41111229050718745;  // exp(-4/4.5)
constexpr double KD2 = 0.80073740291680804;  // exp(-1/4.5)
constexpr double KSUM = 1.0 + 2.0 * (KD0 + KD1 + KD2);

__global__ __launch_bounds__(NTHREADS) void gauss7(const float* __restrict__ in,
                                                   float* __restrict__ out) {
  constexpr float W7[7] = {
      (float)(KD0 / KSUM), (float)(KD1 / KSUM), (float)(KD2 / KSUM),
      (float)(1.0 / KSUM),
      (float)(KD2 / KSUM), (float)(KD1 / KSUM), (float)(KD0 / KSUM)};

  __shared__ float lds[RCH][RF];

  const int b   = blockIdx.x;
  const int n   = b >> 5;   // 32 blocks per batch image
  const int rem = b & 31;
  const int wt  = rem & 7;  // 8 W-tiles
  const int hc  = rem >> 3; // 4 H-chunks
  const int h0  = hc * HCHUNK;
  const int w0  = wt * TW;
  const int tid = threadIdx.x;

  const float* inN  = in  + (size_t)n * HIMG * ROWF;
  float*       outN = out + (size_t)n * HIMG * ROWF;

  // --- vertical role: thread tid owns staged float-column tid (tid < 210) ---
  const bool vact = tid < RF;
  int src_col = 0;
  if (vact) {
    // global float col = w0*3 - 9 + tid ; t9 = that + 9 >= 0
    int t9   = w0 * CH + tid;
    int wpix = t9 / CH - 3;
    int ch   = t9 - (t9 / CH) * CH;
    int wr   = wpix < 0 ? -wpix : (wpix > WIMG - 1 ? 2 * (WIMG - 1) - wpix : wpix);
    src_col  = wr * CH + ch;   // reflect-101 in W, precomputed once
  }

  // rolling window: win[0..5] = input rows [h-3 .. h+2] for next output row h
  float win[6];
  if (vact) {
#pragma unroll
    for (int i = 0; i < 6; ++i) {
      int r  = h0 - 3 + i;
      int rr = r < 0 ? -r : (r > HIMG - 1 ? 2 * (HIMG - 1) - r : r);
      win[i] = inN[(size_t)rr * ROWF + src_col];
    }
  }

  for (int it = 0; it < NITER; ++it) {
    const int hbase = h0 + it * RCH;
    if (vact) {
      float nw[RCH];
#pragma unroll
      for (int i = 0; i < RCH; ++i) {   // 8 loads issued back-to-back (MLP)
        int r  = hbase + 3 + i;         // r >= 3 always; only top reflect in preload
        int rr = r > HIMG - 1 ? 2 * (HIMG - 1) - r : r;
        nw[i]  = inN[(size_t)rr * ROWF + src_col];
      }
#pragma unroll
      for (int i = 0; i < RCH; ++i) {
        float v = W7[0] * win[0] + W7[1] * win[1] + W7[2] * win[2] +
                  W7[3] * win[3] + W7[4] * win[4] + W7[5] * win[5] +
                  W7[6] * nw[i];
#pragma unroll
        for (int j = 0; j < 5; ++j) win[j] = win[j + 1];
        win[5]      = nw[i];
        lds[i][tid] = v;   // lanes write consecutive addresses: conflict-free
      }
    }
    __syncthreads();
    // --- horizontal pass from LDS, all 256 threads ---
#pragma unroll
    for (int k = 0; k < OUTS_PER_THREAD; ++k) {
      int o  = tid + k * NTHREADS;
      int hl = o / TF;
      int f  = o - hl * TF;
      const float* lrow = &lds[hl][f];  // output pixel needs staged floats f .. f+18
      float v = W7[0] * lrow[0]  + W7[1] * lrow[3]  + W7[2] * lrow[6] +
                W7[3] * lrow[9]  + W7[4] * lrow[12] + W7[5] * lrow[15] +
                W7[6] * lrow[18];
      outN[(size_t)(hbase + hl) * ROWF + w0 * CH + f] = v;
    }
    __syncthreads();
  }
}

}  // namespace

extern "C" void kernel_launch(void* const* d_in, const int* in_sizes, int n_in,
                              void* d_out, int out_size, void* d_ws, size_t ws_size,
                              hipStream_t stream) {
  const float* x = (const float*)d_in[0];
  float*       y = (float*)d_out;
  dim3 grid(64 * 8 * 4);  // batch * wtiles * hchunks = 2048 blocks
  dim3 block(NTHREADS);
  hipLaunchKernelGGL(gauss7, grid, block, 0, stream, x, y);
}